// Round 1
// baseline (1249.107 us; speedup 1.0000x reference)
//
#include <hip/hip_runtime.h>
#include <cstdint>

#define NH 16
#define DH 64
#define FF 4096
#define PP 512
#define BB 2048

typedef __bf16 bf16x8 __attribute__((ext_vector_type(8)));
typedef float f32x4 __attribute__((ext_vector_type(4)));
typedef float fl4 __attribute__((ext_vector_type(4)));
typedef unsigned short us4 __attribute__((ext_vector_type(4)));

__device__ __forceinline__ unsigned short f2bf(float f) {
  unsigned u = __float_as_uint(f);
  u += 0x7FFFu + ((u >> 16) & 1u);
  return (unsigned short)(u >> 16);
}

// async global->LDS, 16B per lane. HW semantics: LDS dest = wave-uniform base
// (readfirstlane) + lane*16; our per-lane pointers match that pattern exactly.
__device__ __forceinline__ void gload_lds16(const void* g, void* l) {
  __builtin_amdgcn_global_load_lds(
      (const __attribute__((address_space(1))) void*)g,
      (__attribute__((address_space(3))) void*)(unsigned int)(unsigned long long)l,
      16, 0, 0);
}

__global__ void cvt_bf16(const float* __restrict__ src,
                         unsigned short* __restrict__ dst, int n4) {
  int i = blockIdx.x * blockDim.x + threadIdx.x;
  if (i >= n4) return;
  fl4 v = ((const fl4*)src)[i];
  us4 o;
  o.x = f2bf(v.x); o.y = f2bf(v.y); o.z = f2bf(v.z); o.w = f2bf(v.w);
  ((us4*)dst)[i] = o;
}

// ---------------------------------------------------------------------------
// Phase 1/2: per-head GEMM with K=64 (the head dim).
//   A rows: stride 1024 elems, slice [row][h*64 .. h*64+63]
//   B rows: features, same layout. C[row][f] -> transformed outputs.
// PHASE==1: A=prototypes. Store Q1 = th*Pw+al*Pp-al, Q2 = be*Pw  (layout [h][p][f])
//           and atomicAdd pws[h][p] += be*sum_f Pw.
// PHASE==2: A=x. Store Xw = xf*relu(xf), Xp = relu(xf)   (layout [b][h][f])
// ---------------------------------------------------------------------------
template <int PHASE>
__global__ __launch_bounds__(256, 2) void gemm_k64(
    const unsigned short* __restrict__ Abf, const unsigned short* __restrict__ Fbf,
    unsigned short* __restrict__ O1, unsigned short* __restrict__ O2,
    float* __restrict__ pws,
    const float* __restrict__ theta, const float* __restrict__ alpha,
    const float* __restrict__ beta, int m_base) {
  const int h = blockIdx.z;
  const int n0 = blockIdx.x * 128;   // f tile
  const int lm0 = blockIdx.y * 128;  // local row tile (p or chunk-local b)
  const int t = threadIdx.x;

  __shared__ __align__(16) char As[128 * 128];
  __shared__ __align__(16) char Bs[128 * 128];

  {
    const char* ab = (const char*)(Abf + (size_t)(m_base + lm0) * 1024 + h * 64);
    const char* bb = (const char*)(Fbf + (size_t)n0 * 1024 + h * 64);
#pragma unroll
    for (int r = 0; r < 4; ++r) {
      int o = r * 4096 + t * 16;
      int row = o >> 7, col = o & 127;
      gload_lds16(ab + (size_t)row * 2048 + col, As + o);
      gload_lds16(bb + (size_t)row * 2048 + col, Bs + o);
    }
  }
  __syncthreads();

  const int wave = t >> 6, lane = t & 63;
  const int wm = wave & 1, wn = wave >> 1;
  const int quad = lane >> 4, lr = lane & 15;

  f32x4 acc[4][4];
#pragma unroll
  for (int i = 0; i < 4; ++i)
#pragma unroll
    for (int j = 0; j < 4; ++j) acc[i][j] = (f32x4){0.f, 0.f, 0.f, 0.f};

#pragma unroll
  for (int s = 0; s < 2; ++s) {
    bf16x8 av[4], bv[4];
#pragma unroll
    for (int fm = 0; fm < 4; ++fm) {
      int row = wm * 64 + fm * 16 + lr;
      av[fm] = *(const bf16x8*)(As + row * 128 + s * 64 + quad * 16);
    }
#pragma unroll
    for (int fn = 0; fn < 4; ++fn) {
      int row = wn * 64 + fn * 16 + lr;
      bv[fn] = *(const bf16x8*)(Bs + row * 128 + s * 64 + quad * 16);
    }
#pragma unroll
    for (int fm = 0; fm < 4; ++fm)
#pragma unroll
      for (int fn = 0; fn < 4; ++fn)
        acc[fm][fn] = __builtin_amdgcn_mfma_f32_16x16x32_bf16(av[fm], bv[fn],
                                                              acc[fm][fn], 0, 0, 0);
  }

  const float th = theta[h], al = alpha[h], be = beta[h];

  if (PHASE == 1) {
#pragma unroll
    for (int fm = 0; fm < 4; ++fm) {
      int prow = lm0 + wm * 64 + fm * 16 + quad * 4;
      float rs0 = 0.f, rs1 = 0.f, rs2 = 0.f, rs3 = 0.f;
#pragma unroll
      for (int fn = 0; fn < 4; ++fn) {
        int f = n0 + wn * 64 + fn * 16 + lr;
#pragma unroll
        for (int i = 0; i < 4; ++i) {
          float pf = acc[fm][fn][i];
          float pp = fmaxf(pf, 0.f);
          float pw = pf * pp;
          size_t idx = ((size_t)(h * PP + prow + i)) * FF + f;
          O1[idx] = f2bf(th * pw + al * pp - al);
          O2[idx] = f2bf(be * pw);
          if (i == 0) rs0 += pw;
          else if (i == 1) rs1 += pw;
          else if (i == 2) rs2 += pw;
          else rs3 += pw;
        }
      }
      float rs[4] = {rs0, rs1, rs2, rs3};
#pragma unroll
      for (int i = 0; i < 4; ++i) {
        float s = rs[i];
        s += __shfl_xor(s, 1);
        s += __shfl_xor(s, 2);
        s += __shfl_xor(s, 4);
        s += __shfl_xor(s, 8);
        if (lr == 0) atomicAdd(&pws[h * PP + prow + i], be * s);
      }
    }
  } else {
#pragma unroll
    for (int fm = 0; fm < 4; ++fm) {
      int brow = lm0 + wm * 64 + fm * 16 + quad * 4;
#pragma unroll
      for (int fn = 0; fn < 4; ++fn) {
        int f = n0 + wn * 64 + fn * 16 + lr;
#pragma unroll
        for (int i = 0; i < 4; ++i) {
          float xf = acc[fm][fn][i];
          float xp = fmaxf(xf, 0.f);
          float xw = xf * xp;
          size_t idx = ((size_t)(brow + i) * NH + h) * FF + f;
          O1[idx] = f2bf(xw);
          O2[idx] = f2bf(xp);
        }
      }
    }
  }
}

// ---------------------------------------------------------------------------
// Phase 3: per-head GEMM  out[b][h*512+p] = sum_f Xw*Q1 + Xp*Q2  - pws[h][p]
// M=b (chunk rows), N=p (512), K=8192 (two passes of 4096).
// ---------------------------------------------------------------------------
__global__ __launch_bounds__(256, 2) void gemm_main(
    const unsigned short* __restrict__ Xw, const unsigned short* __restrict__ Xp,
    const unsigned short* __restrict__ Q1, const unsigned short* __restrict__ Q2,
    const float* __restrict__ pws, float* __restrict__ out, int b0) {
  const int h = blockIdx.z;
  const int n0 = blockIdx.x * 128;   // p tile
  const int lm0 = blockIdx.y * 128;  // chunk-local b tile
  const int t = threadIdx.x;

  __shared__ __align__(16) char As[128 * 128];
  __shared__ __align__(16) char Bs[128 * 128];

  const int wave = t >> 6, lane = t & 63;
  const int wm = wave & 1, wn = wave >> 1;
  const int quad = lane >> 4, lr = lane & 15;

  f32x4 acc[4][4];
#pragma unroll
  for (int i = 0; i < 4; ++i)
#pragma unroll
    for (int j = 0; j < 4; ++j) acc[i][j] = (f32x4){0.f, 0.f, 0.f, 0.f};

  const char* abase[2] = {
      (const char*)(Xw + ((size_t)lm0 * NH + h) * FF),
      (const char*)(Xp + ((size_t)lm0 * NH + h) * FF)};
  const char* bbase[2] = {
      (const char*)(Q1 + ((size_t)h * PP + n0) * FF),
      (const char*)(Q2 + ((size_t)h * PP + n0) * FF)};
  const size_t astride = (size_t)NH * FF * 2;  // 131072 B between b rows
  const size_t bstride = (size_t)FF * 2;       // 8192 B between p rows

  for (int pass = 0; pass < 2; ++pass) {
    const char* ab = abase[pass];
    const char* bb = bbase[pass];
    for (int kk = 0; kk < FF; kk += 64) {
#pragma unroll
      for (int r = 0; r < 4; ++r) {
        int o = r * 4096 + t * 16;
        int row = o >> 7, col = o & 127;
        gload_lds16(ab + (size_t)row * astride + (size_t)kk * 2 + col, As + o);
        gload_lds16(bb + (size_t)row * bstride + (size_t)kk * 2 + col, Bs + o);
      }
      __syncthreads();
#pragma unroll
      for (int s = 0; s < 2; ++s) {
        bf16x8 av[4], bv[4];
#pragma unroll
        for (int fm = 0; fm < 4; ++fm) {
          int row = wm * 64 + fm * 16 + lr;
          av[fm] = *(const bf16x8*)(As + row * 128 + s * 64 + quad * 16);
        }
#pragma unroll
        for (int fn = 0; fn < 4; ++fn) {
          int row = wn * 64 + fn * 16 + lr;
          bv[fn] = *(const bf16x8*)(Bs + row * 128 + s * 64 + quad * 16);
        }
#pragma unroll
        for (int fm = 0; fm < 4; ++fm)
#pragma unroll
          for (int fn = 0; fn < 4; ++fn)
            acc[fm][fn] = __builtin_amdgcn_mfma_f32_16x16x32_bf16(
                av[fm], bv[fn], acc[fm][fn], 0, 0, 0);
      }
      __syncthreads();
    }
  }

#pragma unroll
  for (int fn = 0; fn < 4; ++fn) {
    int p = n0 + wn * 64 + fn * 16 + lr;
    float sub = pws[h * PP + p];
#pragma unroll
    for (int fm = 0; fm < 4; ++fm) {
      int brow = b0 + lm0 + wm * 64 + fm * 16 + quad * 4;
#pragma unroll
      for (int i = 0; i < 4; ++i) {
        out[(size_t)(brow + i) * (NH * PP) + h * PP + p] = acc[fm][fn][i] - sub;
      }
    }
  }
}

extern "C" void kernel_launch(void* const* d_in, const int* in_sizes, int n_in,
                              void* d_out, int out_size, void* d_ws, size_t ws_size,
                              hipStream_t stream) {
  const float* x = (const float*)d_in[0];
  const float* features = (const float*)d_in[1];
  const float* prototypes = (const float*)d_in[2];
  const float* theta = (const float*)d_in[3];
  const float* alpha = (const float*)d_in[4];
  const float* beta = (const float*)d_in[5];
  float* out = (float*)d_out;

  char* ws = (char*)d_ws;
  size_t off = 0;
  auto carve = [&](size_t bytes) -> char* {
    char* p = ws + off;
    off += (bytes + 255) & ~(size_t)255;
    return p;
  };
  unsigned short* x_bf = (unsigned short*)carve((size_t)BB * 1024 * 2);
  unsigned short* f_bf = (unsigned short*)carve((size_t)FF * 1024 * 2);
  unsigned short* p_bf = (unsigned short*)carve((size_t)PP * 1024 * 2);
  unsigned short* Q1 = (unsigned short*)carve((size_t)NH * PP * FF * 2);
  unsigned short* Q2 = (unsigned short*)carve((size_t)NH * PP * FF * 2);
  float* pws = (float*)carve((size_t)NH * PP * 4);
  size_t fixed = off;

  // chunk B rows to fit workspace: per-row cost = Xw+Xp = 16*4096*2*2 bytes
  size_t per_row = (size_t)NH * FF * 2 * 2;
  size_t avail = ws_size > fixed ? ws_size - fixed : 0;
  int Bc = (int)((avail / per_row) / 128) * 128;
  if (Bc > BB) Bc = BB;
  if (Bc < 128) Bc = 128;  // minimum viable; if ws is smaller we fail anyway
  unsigned short* Xw = (unsigned short*)carve((size_t)Bc * NH * FF * 2);
  unsigned short* Xp = (unsigned short*)carve((size_t)Bc * NH * FF * 2);

  cvt_bf16<<<2048, 256, 0, stream>>>(x, x_bf, BB * 1024 / 4);
  cvt_bf16<<<4096, 256, 0, stream>>>(features, f_bf, FF * 1024 / 4);
  cvt_bf16<<<512, 256, 0, stream>>>(prototypes, p_bf, PP * 1024 / 4);
  hipMemsetAsync(pws, 0, (size_t)NH * PP * 4, stream);

  // Phase 1: prototypes -> Q1, Q2, pws
  gemm_k64<1><<<dim3(FF / 128, PP / 128, NH), 256, 0, stream>>>(
      p_bf, f_bf, Q1, Q2, pws, theta, alpha, beta, 0);

  for (int b0 = 0; b0 < BB; b0 += Bc) {
    int rows = (BB - b0) < Bc ? (BB - b0) : Bc;
    // Phase 2: x -> Xw, Xp (chunk-local)
    gemm_k64<2><<<dim3(FF / 128, rows / 128, NH), 256, 0, stream>>>(
        x_bf, f_bf, Xw, Xp, nullptr, theta, alpha, beta, b0);
    // Phase 3: main GEMM + epilogue
    gemm_main<<<dim3(PP / 128, rows / 128, NH), 256, 0, stream>>>(
        Xw, Xp, Q1, Q2, pws, out, b0);
  }
}

// Round 2
// 490.789 us; speedup vs baseline: 2.5451x; 2.5451x over previous
//
#include <hip/hip_runtime.h>
#include <cstdint>

#define NH 16
#define DH 64
#define FF 4096
#define PP 512
#define BB 2048

typedef __bf16 bf16x8 __attribute__((ext_vector_type(8)));
typedef float f32x4 __attribute__((ext_vector_type(4)));
typedef float fl4 __attribute__((ext_vector_type(4)));
typedef unsigned short us4 __attribute__((ext_vector_type(4)));

__device__ __forceinline__ unsigned short f2bf(float f) {
  unsigned u = __float_as_uint(f);
  u += 0x7FFFu + ((u >> 16) & 1u);
  return (unsigned short)(u >> 16);
}

// async global->LDS, 16B/lane. LDS dest must be wave-uniform base + lane*16;
// source address is per-lane arbitrary (we exploit that for the XOR swizzle).
__device__ __forceinline__ void gload_lds16(const void* g, void* l) {
  __builtin_amdgcn_global_load_lds(
      (const __attribute__((address_space(1))) void*)g,
      (__attribute__((address_space(3))) void*)(unsigned int)(unsigned long long)l,
      16, 0, 0);
}

__global__ void cvt_bf16(const float* __restrict__ src,
                         unsigned short* __restrict__ dst, int n4) {
  int i = blockIdx.x * blockDim.x + threadIdx.x;
  if (i >= n4) return;
  fl4 v = ((const fl4*)src)[i];
  us4 o;
  o.x = f2bf(v.x); o.y = f2bf(v.y); o.z = f2bf(v.z); o.w = f2bf(v.w);
  ((us4*)dst)[i] = o;
}

// ---------------------------------------------------------------------------
// Phase 1: per-head [P x F, K=64] GEMM on prototypes.
//   Q1 = th*Pw + al*Pp - al,  Q2 = be*Pw   (layout [h][p][f], bf16)
//   pws[h][p] += be * sum_f Pw
// ---------------------------------------------------------------------------
__global__ __launch_bounds__(256, 2) void gemm_proto(
    const unsigned short* __restrict__ Abf, const unsigned short* __restrict__ Fbf,
    unsigned short* __restrict__ O1, unsigned short* __restrict__ O2,
    float* __restrict__ pws,
    const float* __restrict__ theta, const float* __restrict__ alpha,
    const float* __restrict__ beta) {
  const int h = blockIdx.z;
  const int n0 = blockIdx.x * 128;   // f tile
  const int lm0 = blockIdx.y * 128;  // p tile
  const int t = threadIdx.x;

  __shared__ __align__(16) char As[128 * 128];
  __shared__ __align__(16) char Bs[128 * 128];

  {
    const char* ab = (const char*)(Abf + (size_t)lm0 * 1024 + h * 64);
    const char* bb = (const char*)(Fbf + (size_t)n0 * 1024 + h * 64);
#pragma unroll
    for (int r = 0; r < 4; ++r) {
      int o = r * 4096 + t * 16;
      int row = o >> 7, col = o & 127;
      gload_lds16(ab + (size_t)row * 2048 + col, As + o);
      gload_lds16(bb + (size_t)row * 2048 + col, Bs + o);
    }
  }
  __syncthreads();

  const int wave = t >> 6, lane = t & 63;
  const int wm = wave & 1, wn = wave >> 1;
  const int quad = lane >> 4, lr = lane & 15;

  f32x4 acc[4][4];
#pragma unroll
  for (int i = 0; i < 4; ++i)
#pragma unroll
    for (int j = 0; j < 4; ++j) acc[i][j] = (f32x4){0.f, 0.f, 0.f, 0.f};

#pragma unroll
  for (int s = 0; s < 2; ++s) {
    bf16x8 av[4], bv[4];
#pragma unroll
    for (int fm = 0; fm < 4; ++fm) {
      int row = wm * 64 + fm * 16 + lr;
      av[fm] = *(const bf16x8*)(As + row * 128 + s * 64 + quad * 16);
    }
#pragma unroll
    for (int fn = 0; fn < 4; ++fn) {
      int row = wn * 64 + fn * 16 + lr;
      bv[fn] = *(const bf16x8*)(Bs + row * 128 + s * 64 + quad * 16);
    }
#pragma unroll
    for (int fm = 0; fm < 4; ++fm)
#pragma unroll
      for (int fn = 0; fn < 4; ++fn)
        acc[fm][fn] = __builtin_amdgcn_mfma_f32_16x16x32_bf16(av[fm], bv[fn],
                                                              acc[fm][fn], 0, 0, 0);
  }

  const float th = theta[h], al = alpha[h], be = beta[h];

#pragma unroll
  for (int fm = 0; fm < 4; ++fm) {
    int prow = lm0 + wm * 64 + fm * 16 + quad * 4;
    float rs0 = 0.f, rs1 = 0.f, rs2 = 0.f, rs3 = 0.f;
#pragma unroll
    for (int fn = 0; fn < 4; ++fn) {
      int f = n0 + wn * 64 + fn * 16 + lr;
#pragma unroll
      for (int i = 0; i < 4; ++i) {
        float pf = acc[fm][fn][i];
        float pp = fmaxf(pf, 0.f);
        float pw = pf * pp;
        size_t idx = ((size_t)(h * PP + prow + i)) * FF + f;
        O1[idx] = f2bf(th * pw + al * pp - al);
        O2[idx] = f2bf(be * pw);
        if (i == 0) rs0 += pw;
        else if (i == 1) rs1 += pw;
        else if (i == 2) rs2 += pw;
        else rs3 += pw;
      }
    }
    float rs[4] = {rs0, rs1, rs2, rs3};
#pragma unroll
    for (int i = 0; i < 4; ++i) {
      float s = rs[i];
      s += __shfl_xor(s, 1);
      s += __shfl_xor(s, 2);
      s += __shfl_xor(s, 4);
      s += __shfl_xor(s, 8);
      if (lr == 0) atomicAdd(&pws[h * PP + prow + i], be * s);
    }
  }
}

// ---------------------------------------------------------------------------
// Fused main: per (p-tile 128, b-tile 128, head) block, single pass over F.
// Per f-tile of 64:
//   step A: stage Fh(64x64), Q1(128x64), Q2(128x64) via global_load_lds with
//           16B-chunk XOR swizzle (chunk c of row r lands at c^(r&7)).
//   step B: Xf[f][b] = Fh . Xh^T via MFMA (Xh fragments in registers).
//   step C: Xw = xf*relu(xf), Xp = relu(xf) -> packed 8B LDS writes (swizzled).
//   step D: acc += Xw.Q1^T + Xp.Q2^T  (2 MFMA chains, one accumulator).
// Epilogue: out[b][h*512+p] = acc - pws[h][p].
// LDS = 8+16+16+16+16 = 72 KB -> 2 blocks/CU.
// ---------------------------------------------------------------------------
__global__ __launch_bounds__(256, 2) void fused_main(
    const unsigned short* __restrict__ x_bf, const unsigned short* __restrict__ f_bf,
    const unsigned short* __restrict__ Q1, const unsigned short* __restrict__ Q2,
    const float* __restrict__ pws, float* __restrict__ out) {
  const int h = blockIdx.z;
  const int n0 = blockIdx.x * 128;  // p tile
  const int m0 = blockIdx.y * 128;  // b tile
  const int t = threadIdx.x;
  const int wave = t >> 6, lane = t & 63;
  const int wm = wave & 1, wn = wave >> 1;
  const int quad = lane >> 4, lr = lane & 15;
  const int sw = lr & 7;  // per-lane XOR swizzle key (== row&7 for frag reads)

  __shared__ __align__(16) char sF[8192];
  __shared__ __align__(16) char sQ1[16384];
  __shared__ __align__(16) char sQ2[16384];
  __shared__ __align__(16) char sXw[16384];
  __shared__ __align__(16) char sXp[16384];

  // Xh B-operand fragments in registers: wave covers b = m0+wave*32 .. +31
  bf16x8 xh[2][2];  // [bn][s] ; k = s*32 + quad*8 + j over d=64
#pragma unroll
  for (int bn = 0; bn < 2; ++bn)
#pragma unroll
    for (int s = 0; s < 2; ++s) {
      int b = m0 + wave * 32 + bn * 16 + lr;
      xh[bn][s] = *(const bf16x8*)(x_bf + (size_t)b * 1024 + h * 64 + s * 32 + quad * 8);
    }

  // staging source pointers (swizzled on the GLOBAL side)
  const char* srcF[2];
  const char* srcQ1[4];
  const char* srcQ2[4];
  {
    const char* fb = (const char*)f_bf + h * 128;
    const char* q1b = (const char*)(Q1 + ((size_t)h * PP + n0) * FF);
    const char* q2b = (const char*)(Q2 + ((size_t)h * PP + n0) * FF);
#pragma unroll
    for (int r = 0; r < 2; ++r) {
      int ci = r * 256 + t, row = ci >> 3, c = ci & 7, cs = c ^ (row & 7);
      srcF[r] = fb + (size_t)row * 2048 + cs * 16;
    }
#pragma unroll
    for (int r = 0; r < 4; ++r) {
      int ci = r * 256 + t, row = ci >> 3, c = ci & 7, cs = c ^ (row & 7);
      srcQ1[r] = q1b + (size_t)row * 8192 + cs * 16;
      srcQ2[r] = q2b + (size_t)row * 8192 + cs * 16;
    }
  }

  f32x4 acc[4][4];
#pragma unroll
  for (int i = 0; i < 4; ++i)
#pragma unroll
    for (int j = 0; j < 4; ++j) acc[i][j] = (f32x4){0.f, 0.f, 0.f, 0.f};

  for (int kk = 0; kk < FF; kk += 64) {
    __syncthreads();  // previous iteration's LDS reads complete
#pragma unroll
    for (int r = 0; r < 2; ++r) gload_lds16(srcF[r], sF + r * 4096 + t * 16);
#pragma unroll
    for (int r = 0; r < 4; ++r) {
      gload_lds16(srcQ1[r], sQ1 + r * 4096 + t * 16);
      gload_lds16(srcQ2[r], sQ2 + r * 4096 + t * 16);
    }
    srcF[0] += 64 * 2048; srcF[1] += 64 * 2048;
#pragma unroll
    for (int r = 0; r < 4; ++r) { srcQ1[r] += 128; srcQ2[r] += 128; }
    __syncthreads();  // staging complete (vmcnt drained by barrier)

    // step B: Xf[f 0..63][b wave*32..+31], m=f n=b, K=d=64
    f32x4 xf[4][2];
#pragma unroll
    for (int fm = 0; fm < 4; ++fm)
#pragma unroll
      for (int bn = 0; bn < 2; ++bn) xf[fm][bn] = (f32x4){0.f, 0.f, 0.f, 0.f};
#pragma unroll
    for (int s = 0; s < 2; ++s)
#pragma unroll
      for (int fm = 0; fm < 4; ++fm) {
        int row = fm * 16 + lr;
        bf16x8 af = *(const bf16x8*)(sF + row * 128 + (((s * 4 + quad) ^ sw) * 16));
#pragma unroll
        for (int bn = 0; bn < 2; ++bn)
          xf[fm][bn] = __builtin_amdgcn_mfma_f32_16x16x32_bf16(af, xh[bn][s],
                                                               xf[fm][bn], 0, 0, 0);
      }

    // step C: transform + pack to LDS. C-layout: lane holds f = fm*16+quad*4+i,
    // b = wave*32+bn*16+lr  ->  4 consecutive f for one b -> one 8B write.
#pragma unroll
    for (int fm = 0; fm < 4; ++fm)
#pragma unroll
      for (int bn = 0; bn < 2; ++bn) {
        int rb = wave * 32 + bn * 16 + lr;
        us4 pw, pp;
#pragma unroll
        for (int i = 0; i < 4; ++i) {
          float v = xf[fm][bn][i];
          float p = fmaxf(v, 0.f);
          float w = v * p;
          pw[i] = f2bf(w);
          pp[i] = f2bf(p);
        }
        int off = rb * 128 + (((fm * 2 + (quad >> 1)) ^ sw) * 16) + (quad & 1) * 8;
        *(us4*)(sXw + off) = pw;
        *(us4*)(sXp + off) = pp;
      }
    __syncthreads();  // Xw/Xp visible to all waves

    // step D: acc += Xw.Q1^T + Xp.Q2^T over this f-tile (K=64)
#pragma unroll
    for (int s = 0; s < 2; ++s) {
      bf16x8 aw[4], ap[4], b1[4], b2[4];
#pragma unroll
      for (int fm = 0; fm < 4; ++fm) {
        int row = wm * 64 + fm * 16 + lr;
        int off = row * 128 + (((s * 4 + quad) ^ sw) * 16);
        aw[fm] = *(const bf16x8*)(sXw + off);
        ap[fm] = *(const bf16x8*)(sXp + off);
      }
#pragma unroll
      for (int fn = 0; fn < 4; ++fn) {
        int row = wn * 64 + fn * 16 + lr;
        int off = row * 128 + (((s * 4 + quad) ^ sw) * 16);
        b1[fn] = *(const bf16x8*)(sQ1 + off);
        b2[fn] = *(const bf16x8*)(sQ2 + off);
      }
#pragma unroll
      for (int fm = 0; fm < 4; ++fm)
#pragma unroll
        for (int fn = 0; fn < 4; ++fn) {
          acc[fm][fn] = __builtin_amdgcn_mfma_f32_16x16x32_bf16(aw[fm], b1[fn],
                                                                acc[fm][fn], 0, 0, 0);
          acc[fm][fn] = __builtin_amdgcn_mfma_f32_16x16x32_bf16(ap[fm], b2[fn],
                                                                acc[fm][fn], 0, 0, 0);
        }
    }
  }

  // epilogue: subtract pws, store fp32
#pragma unroll
  for (int fn = 0; fn < 4; ++fn) {
    int p = n0 + wn * 64 + fn * 16 + lr;
    float sub = pws[h * PP + p];
#pragma unroll
    for (int fm = 0; fm < 4; ++fm) {
      int brow = m0 + wm * 64 + fm * 16 + quad * 4;
#pragma unroll
      for (int i = 0; i < 4; ++i) {
        out[(size_t)(brow + i) * (NH * PP) + h * PP + p] = acc[fm][fn][i] - sub;
      }
    }
  }
}

extern "C" void kernel_launch(void* const* d_in, const int* in_sizes, int n_in,
                              void* d_out, int out_size, void* d_ws, size_t ws_size,
                              hipStream_t stream) {
  const float* x = (const float*)d_in[0];
  const float* features = (const float*)d_in[1];
  const float* prototypes = (const float*)d_in[2];
  const float* theta = (const float*)d_in[3];
  const float* alpha = (const float*)d_in[4];
  const float* beta = (const float*)d_in[5];
  float* out = (float*)d_out;

  char* ws = (char*)d_ws;
  size_t off = 0;
  auto carve = [&](size_t bytes) -> char* {
    char* p = ws + off;
    off += (bytes + 255) & ~(size_t)255;
    return p;
  };
  unsigned short* x_bf = (unsigned short*)carve((size_t)BB * 1024 * 2);
  unsigned short* f_bf = (unsigned short*)carve((size_t)FF * 1024 * 2);
  unsigned short* p_bf = (unsigned short*)carve((size_t)PP * 1024 * 2);
  unsigned short* Q1 = (unsigned short*)carve((size_t)NH * PP * FF * 2);
  unsigned short* Q2 = (unsigned short*)carve((size_t)NH * PP * FF * 2);
  float* pws = (float*)carve((size_t)NH * PP * 4);

  cvt_bf16<<<2048, 256, 0, stream>>>(x, x_bf, BB * 1024 / 4);
  cvt_bf16<<<4096, 256, 0, stream>>>(features, f_bf, FF * 1024 / 4);
  cvt_bf16<<<512, 256, 0, stream>>>(prototypes, p_bf, PP * 1024 / 4);
  hipMemsetAsync(pws, 0, (size_t)NH * PP * 4, stream);

  // Phase 1: prototypes -> Q1, Q2, pws
  gemm_proto<<<dim3(FF / 128, PP / 128, NH), 256, 0, stream>>>(
      p_bf, f_bf, Q1, Q2, pws, theta, alpha, beta);

  // Fused main GEMM
  fused_main<<<dim3(PP / 128, BB / 128, NH), 256, 0, stream>>>(
      x_bf, f_bf, Q1, Q2, pws, out);
}

// Round 3
// 423.255 us; speedup vs baseline: 2.9512x; 1.1596x over previous
//
#include <hip/hip_runtime.h>
#include <cstdint>

#define NH 16
#define DH 64
#define FF 4096
#define PP 512
#define BB 2048

typedef __bf16 bf16x8 __attribute__((ext_vector_type(8)));
typedef float f32x4 __attribute__((ext_vector_type(4)));
typedef float fl4 __attribute__((ext_vector_type(4)));
typedef unsigned short us4 __attribute__((ext_vector_type(4)));
typedef unsigned int u32x2 __attribute__((ext_vector_type(2)));

__device__ __forceinline__ unsigned short f2bf(float f) {
  unsigned u = __float_as_uint(f);
  u += 0x7FFFu + ((u >> 16) & 1u);
  return (unsigned short)(u >> 16);
}

// pack two f32 -> two bf16 (round-half-up: +0x8000 then take high 16 via v_perm)
__device__ __forceinline__ unsigned int pkbf(float lo, float hi) {
  unsigned a = __float_as_uint(lo) + 0x8000u;
  unsigned b = __float_as_uint(hi) + 0x8000u;
  return __builtin_amdgcn_perm(b, a, 0x07060302u);  // [b.hi16 : a.hi16]
}

// async global->LDS, 16B/lane. LDS dest must be wave-uniform base + lane*16;
// global source is per-lane arbitrary (exploited for the XOR swizzle).
__device__ __forceinline__ void gload_lds16(const void* g, void* l) {
  __builtin_amdgcn_global_load_lds(
      (const __attribute__((address_space(1))) void*)g,
      (__attribute__((address_space(3))) void*)(unsigned int)(unsigned long long)l,
      16, 0, 0);
}

__global__ void cvt_bf16(const float* __restrict__ src,
                         unsigned short* __restrict__ dst, int n4) {
  int i = blockIdx.x * blockDim.x + threadIdx.x;
  if (i >= n4) return;
  fl4 v = ((const fl4*)src)[i];
  us4 o;
  o.x = f2bf(v.x); o.y = f2bf(v.y); o.z = f2bf(v.z); o.w = f2bf(v.w);
  ((us4*)dst)[i] = o;
}

// ---------------------------------------------------------------------------
// Phase 1: per-head [P x F, K=64] GEMM on prototypes.
//   Q1 = th*Pw + al*Pp - al,  Q2 = be*Pw   (layout [h][p][f], bf16)
//   pws[h][p] += be * sum_f Pw
// ---------------------------------------------------------------------------
__global__ __launch_bounds__(256, 2) void gemm_proto(
    const unsigned short* __restrict__ Abf, const unsigned short* __restrict__ Fbf,
    unsigned short* __restrict__ O1, unsigned short* __restrict__ O2,
    float* __restrict__ pws,
    const float* __restrict__ theta, const float* __restrict__ alpha,
    const float* __restrict__ beta) {
  const int h = blockIdx.z;
  const int n0 = blockIdx.x * 128;   // f tile
  const int lm0 = blockIdx.y * 128;  // p tile
  const int t = threadIdx.x;

  __shared__ __align__(16) char As[128 * 128];
  __shared__ __align__(16) char Bs[128 * 128];

  {
    const char* ab = (const char*)(Abf + (size_t)lm0 * 1024 + h * 64);
    const char* bb = (const char*)(Fbf + (size_t)n0 * 1024 + h * 64);
#pragma unroll
    for (int r = 0; r < 4; ++r) {
      int o = r * 4096 + t * 16;
      int row = o >> 7, col = o & 127;
      gload_lds16(ab + (size_t)row * 2048 + col, As + o);
      gload_lds16(bb + (size_t)row * 2048 + col, Bs + o);
    }
  }
  __syncthreads();

  const int wave = t >> 6, lane = t & 63;
  const int wm = wave & 1, wn = wave >> 1;
  const int quad = lane >> 4, lr = lane & 15;

  f32x4 acc[4][4];
#pragma unroll
  for (int i = 0; i < 4; ++i)
#pragma unroll
    for (int j = 0; j < 4; ++j) acc[i][j] = (f32x4){0.f, 0.f, 0.f, 0.f};

#pragma unroll
  for (int s = 0; s < 2; ++s) {
    bf16x8 av[4], bv[4];
#pragma unroll
    for (int fm = 0; fm < 4; ++fm) {
      int row = wm * 64 + fm * 16 + lr;
      av[fm] = *(const bf16x8*)(As + row * 128 + s * 64 + quad * 16);
    }
#pragma unroll
    for (int fn = 0; fn < 4; ++fn) {
      int row = wn * 64 + fn * 16 + lr;
      bv[fn] = *(const bf16x8*)(Bs + row * 128 + s * 64 + quad * 16);
    }
#pragma unroll
    for (int fm = 0; fm < 4; ++fm)
#pragma unroll
      for (int fn = 0; fn < 4; ++fn)
        acc[fm][fn] = __builtin_amdgcn_mfma_f32_16x16x32_bf16(av[fm], bv[fn],
                                                              acc[fm][fn], 0, 0, 0);
  }

  const float th = theta[h], al = alpha[h], be = beta[h];

#pragma unroll
  for (int fm = 0; fm < 4; ++fm) {
    int prow = lm0 + wm * 64 + fm * 16 + quad * 4;
    float rs0 = 0.f, rs1 = 0.f, rs2 = 0.f, rs3 = 0.f;
#pragma unroll
    for (int fn = 0; fn < 4; ++fn) {
      int f = n0 + wn * 64 + fn * 16 + lr;
#pragma unroll
      for (int i = 0; i < 4; ++i) {
        float pf = acc[fm][fn][i];
        float pp = fmaxf(pf, 0.f);
        float pw = pf * pp;
        size_t idx = ((size_t)(h * PP + prow + i)) * FF + f;
        O1[idx] = f2bf(th * pw + al * pp - al);
        O2[idx] = f2bf(be * pw);
        if (i == 0) rs0 += pw;
        else if (i == 1) rs1 += pw;
        else if (i == 2) rs2 += pw;
        else rs3 += pw;
      }
    }
    float rs[4] = {rs0, rs1, rs2, rs3};
#pragma unroll
    for (int i = 0; i < 4; ++i) {
      float s = rs[i];
      s += __shfl_xor(s, 1);
      s += __shfl_xor(s, 2);
      s += __shfl_xor(s, 4);
      s += __shfl_xor(s, 8);
      if (lr == 0) atomicAdd(&pws[h * PP + prow + i], be * s);
    }
  }
}

// ---------------------------------------------------------------------------
// Fused main: per (p-tile 256, b-tile 128, head) block, single pass over F
// in steps of KT=32. Per f-step:
//   A: stage Fh(32x64), Q1(256x32), Q2(256x32) via swizzled global_load_lds.
//   B: Xf[f][b] = Fh . Xh^T via MFMA (Xh fragments in registers).
//   C: Xw = xf*relu(xf), Xp = relu(xf) -> packed 8B LDS writes (swizzled).
//   D: acc += Xw.Q1^T + Xp.Q2^T  (one accumulator, 64 MFMA/wave).
// Recompute overhead = 32/256 = 12.5% of MFMA. LDS = 4+16+16+8+8 = 52 KB
// -> 2 blocks/CU; grid 2x16x16 = 512 = exactly full residency.
// ---------------------------------------------------------------------------
__global__ __launch_bounds__(256, 2) void fused_main(
    const unsigned short* __restrict__ x_bf, const unsigned short* __restrict__ f_bf,
    const unsigned short* __restrict__ Q1, const unsigned short* __restrict__ Q2,
    const float* __restrict__ pws, float* __restrict__ out) {
  const int h = blockIdx.z;
  const int n0 = blockIdx.x * 256;  // p tile
  const int m0 = blockIdx.y * 128;  // b tile
  const int t = threadIdx.x;
  const int wave = t >> 6, lane = t & 63;
  const int wm = wave & 1, wn = wave >> 1;
  const int quad = lane >> 4, lr = lane & 15;
  const int key8 = lr & 7;         // swizzle key for 128B-row buffer (sF)
  const int key2 = (lr >> 1) & 3;  // swizzle key for 64B-row buffers (sQ/sX)

  __shared__ __align__(16) char sF[4096];
  __shared__ __align__(16) char sQ1[16384];
  __shared__ __align__(16) char sQ2[16384];
  __shared__ __align__(16) char sXw[8192];
  __shared__ __align__(16) char sXp[8192];

  // Xh B-operand fragments (b = m0 + wave*32 .. +31, k = d)
  bf16x8 xh[2][2];  // [bn][s]: k = s*32 + quad*8 + j
#pragma unroll
  for (int bn = 0; bn < 2; ++bn)
#pragma unroll
    for (int s = 0; s < 2; ++s) {
      int b = m0 + wave * 32 + bn * 16 + lr;
      xh[bn][s] = *(const bf16x8*)(x_bf + (size_t)b * 1024 + h * 64 + s * 32 + quad * 8);
    }

  // ---- hoisted (loop-invariant) LDS byte offsets ----
  int af_off[2][2];  // step B reads: sF row fm*16+lr, global chunk s*4+quad
#pragma unroll
  for (int fm = 0; fm < 2; ++fm)
#pragma unroll
    for (int s = 0; s < 2; ++s)
      af_off[fm][s] = (fm * 16 + lr) * 128 + (((s * 4 + quad) ^ key8) * 16);

  int cw_off[2][2];  // step C writes: row wave*32+bn*16+lr, logical chunk fm*2+(quad>>1)
#pragma unroll
  for (int fm = 0; fm < 2; ++fm)
#pragma unroll
    for (int bn = 0; bn < 2; ++bn)
      cw_off[fm][bn] = (wave * 32 + bn * 16 + lr) * 64 +
                       (((fm * 2 + (quad >> 1)) ^ key2) * 16) + (quad & 1) * 8;

  int aw_off[4];  // step D A reads: row wm*64+fm*16+lr, chunk quad
#pragma unroll
  for (int fm = 0; fm < 4; ++fm)
    aw_off[fm] = (wm * 64 + fm * 16 + lr) * 64 + ((quad ^ key2) * 16);

  int bq_off[8];  // step D B reads: row wn*128+fn*16+lr, chunk quad
#pragma unroll
  for (int fn = 0; fn < 8; ++fn)
    bq_off[fn] = (wn * 128 + fn * 16 + lr) * 64 + ((quad ^ key2) * 16);

  // ---- staging source pointers (swizzle applied on the GLOBAL side) ----
  const char* srcF;
  {
    int row = t >> 3, c = t & 7, cs = c ^ (row & 7);
    srcF = (const char*)f_bf + h * 128 + (size_t)row * 2048 + cs * 16;
  }
  const char* srcQ1[4];
  const char* srcQ2[4];
  {
    const char* q1b = (const char*)(Q1 + ((size_t)h * PP + n0) * FF);
    const char* q2b = (const char*)(Q2 + ((size_t)h * PP + n0) * FF);
#pragma unroll
    for (int r = 0; r < 4; ++r) {
      int ci = r * 256 + t, row = ci >> 2, c = ci & 3, cs = c ^ ((row >> 1) & 3);
      srcQ1[r] = q1b + (size_t)row * 8192 + cs * 16;
      srcQ2[r] = q2b + (size_t)row * 8192 + cs * 16;
    }
  }

  f32x4 acc[4][8];
#pragma unroll
  for (int i = 0; i < 4; ++i)
#pragma unroll
    for (int j = 0; j < 8; ++j) acc[i][j] = (f32x4){0.f, 0.f, 0.f, 0.f};

  for (int it = 0; it < FF / 32; ++it) {
    __syncthreads();  // previous iteration's LDS reads complete
    gload_lds16(srcF, sF + t * 16);
    srcF += 32 * 2048;
#pragma unroll
    for (int r = 0; r < 4; ++r) {
      gload_lds16(srcQ1[r], sQ1 + r * 4096 + t * 16);
      gload_lds16(srcQ2[r], sQ2 + r * 4096 + t * 16);
      srcQ1[r] += 64;
      srcQ2[r] += 64;
    }
    __syncthreads();  // staging visible

    // step B: Xf[f 0..31][b wave*32..+31]
    f32x4 xf[2][2];
#pragma unroll
    for (int fm = 0; fm < 2; ++fm)
#pragma unroll
      for (int bn = 0; bn < 2; ++bn) xf[fm][bn] = (f32x4){0.f, 0.f, 0.f, 0.f};
#pragma unroll
    for (int s = 0; s < 2; ++s)
#pragma unroll
      for (int fm = 0; fm < 2; ++fm) {
        bf16x8 af = *(const bf16x8*)(sF + af_off[fm][s]);
#pragma unroll
        for (int bn = 0; bn < 2; ++bn)
          xf[fm][bn] = __builtin_amdgcn_mfma_f32_16x16x32_bf16(af, xh[bn][s],
                                                               xf[fm][bn], 0, 0, 0);
      }

    // step C: transform + pack (lane holds f = fm*16+quad*4+i, b = wave*32+bn*16+lr)
#pragma unroll
    for (int fm = 0; fm < 2; ++fm)
#pragma unroll
      for (int bn = 0; bn < 2; ++bn) {
        float v0 = xf[fm][bn][0], v1 = xf[fm][bn][1];
        float v2 = xf[fm][bn][2], v3 = xf[fm][bn][3];
        float p0 = fmaxf(v0, 0.f), p1 = fmaxf(v1, 0.f);
        float p2 = fmaxf(v2, 0.f), p3 = fmaxf(v3, 0.f);
        u32x2 w, p;
        w.x = pkbf(v0 * p0, v1 * p1);
        w.y = pkbf(v2 * p2, v3 * p3);
        p.x = pkbf(p0, p1);
        p.y = pkbf(p2, p3);
        *(u32x2*)(sXw + cw_off[fm][bn]) = w;
        *(u32x2*)(sXp + cw_off[fm][bn]) = p;
      }
    __syncthreads();  // Xw/Xp visible

    // step D: acc += Xw.Q1^T + Xp.Q2^T  (K=32)
    bf16x8 aw[4], ap[4];
#pragma unroll
    for (int fm = 0; fm < 4; ++fm) {
      aw[fm] = *(const bf16x8*)(sXw + aw_off[fm]);
      ap[fm] = *(const bf16x8*)(sXp + aw_off[fm]);
    }
#pragma unroll
    for (int fn = 0; fn < 8; ++fn) {
      bf16x8 b1 = *(const bf16x8*)(sQ1 + bq_off[fn]);
      bf16x8 b2 = *(const bf16x8*)(sQ2 + bq_off[fn]);
#pragma unroll
      for (int fm = 0; fm < 4; ++fm) {
        acc[fm][fn] = __builtin_amdgcn_mfma_f32_16x16x32_bf16(aw[fm], b1,
                                                              acc[fm][fn], 0, 0, 0);
        acc[fm][fn] = __builtin_amdgcn_mfma_f32_16x16x32_bf16(ap[fm], b2,
                                                              acc[fm][fn], 0, 0, 0);
      }
    }
  }

  // epilogue: subtract pws, store fp32
#pragma unroll
  for (int fn = 0; fn < 8; ++fn) {
    int p = n0 + wn * 128 + fn * 16 + lr;
    float sub = pws[h * PP + p];
#pragma unroll
    for (int fm = 0; fm < 4; ++fm) {
      int brow = m0 + wm * 64 + fm * 16 + quad * 4;
#pragma unroll
      for (int i = 0; i < 4; ++i) {
        out[(size_t)(brow + i) * (NH * PP) + h * PP + p] = acc[fm][fn][i] - sub;
      }
    }
  }
}

extern "C" void kernel_launch(void* const* d_in, const int* in_sizes, int n_in,
                              void* d_out, int out_size, void* d_ws, size_t ws_size,
                              hipStream_t stream) {
  const float* x = (const float*)d_in[0];
  const float* features = (const float*)d_in[1];
  const float* prototypes = (const float*)d_in[2];
  const float* theta = (const float*)d_in[3];
  const float* alpha = (const float*)d_in[4];
  const float* beta = (const float*)d_in[5];
  float* out = (float*)d_out;

  char* ws = (char*)d_ws;
  size_t off = 0;
  auto carve = [&](size_t bytes) -> char* {
    char* p = ws + off;
    off += (bytes + 255) & ~(size_t)255;
    return p;
  };
  unsigned short* x_bf = (unsigned short*)carve((size_t)BB * 1024 * 2);
  unsigned short* f_bf = (unsigned short*)carve((size_t)FF * 1024 * 2);
  unsigned short* p_bf = (unsigned short*)carve((size_t)PP * 1024 * 2);
  unsigned short* Q1 = (unsigned short*)carve((size_t)NH * PP * FF * 2);
  unsigned short* Q2 = (unsigned short*)carve((size_t)NH * PP * FF * 2);
  float* pws = (float*)carve((size_t)NH * PP * 4);

  cvt_bf16<<<2048, 256, 0, stream>>>(x, x_bf, BB * 1024 / 4);
  cvt_bf16<<<4096, 256, 0, stream>>>(features, f_bf, FF * 1024 / 4);
  cvt_bf16<<<512, 256, 0, stream>>>(prototypes, p_bf, PP * 1024 / 4);
  hipMemsetAsync(pws, 0, (size_t)NH * PP * 4, stream);

  // Phase 1: prototypes -> Q1, Q2, pws
  gemm_proto<<<dim3(FF / 128, PP / 128, NH), 256, 0, stream>>>(
      p_bf, f_bf, Q1, Q2, pws, theta, alpha, beta);

  // Fused main GEMM
  fused_main<<<dim3(PP / 256, BB / 128, NH), 256, 0, stream>>>(
      x_bf, f_bf, Q1, Q2, pws, out);
}